// Round 11
// baseline (339.747 us; speedup 1.0000x reference)
//
#include <hip/hip_runtime.h>
#include <cstdint>
#include <cstddef>

#define B_ 16384
#define K_ 512
#define H_ 4096
#define O_ 512

typedef __attribute__((ext_vector_type(4))) float f32x4;
typedef __attribute__((ext_vector_type(8))) short bf16x8;

#define EPS_FLAG 0.125f

// ---------------------------------------------------------------------------
// Exact helpers (bitwise vs numpy reference — proven in rounds 1-10)
// ---------------------------------------------------------------------------
__device__ inline unsigned short f32_to_bf16_rne(float f) {
  unsigned u = __float_as_uint(f);
  unsigned r = (u + 0x7fffu + ((u >> 16) & 1u)) >> 16;
  return (unsigned short)r;
}

__device__ float np_pairwise_sumsq512(const float* __restrict__ a) {
  float s[4];
  #pragma unroll
  for (int blk = 0; blk < 4; ++blk) {
    const float* p = a + blk * 128;
    float r[8];
    #pragma unroll
    for (int j = 0; j < 8; ++j) r[j] = __fmul_rn(p[j], p[j]);
    for (int i = 8; i < 128; i += 8) {
      #pragma unroll
      for (int j = 0; j < 8; ++j) r[j] = __fadd_rn(r[j], __fmul_rn(p[i + j], p[i + j]));
    }
    s[blk] = __fadd_rn(__fadd_rn(__fadd_rn(r[0], r[1]), __fadd_rn(r[2], r[3])),
                       __fadd_rn(__fadd_rn(r[4], r[5]), __fadd_rn(r[6], r[7])));
  }
  return __fadd_rn(__fadd_rn(s[0], s[1]), __fadd_rn(s[2], s[3]));
}

// Fused: coalesced load of 8 rows -> LDS; emit bf16(hi) coalesced; numpy
// pairwise-order sumsq with 32 lanes/row (bitwise == np_pairwise_sumsq512).
__global__ __launch_bounds__(256) void prep_rows_kernel(
    const float* __restrict__ src, unsigned short* __restrict__ hi,
    float* __restrict__ sumsq, int nrows) {
  __shared__ float buf[8 * 512];
  const int r0 = blockIdx.x * 8;
  const int tid = (int)threadIdx.x;

  #pragma unroll
  for (int it = 0; it < 4; ++it) {
    int i = tid + it * 256;
    float4 v = ((const float4*)(src + (size_t)r0 * K_))[i];
    ((float4*)buf)[i] = v;
    ushort4 h;
    h.x = f32_to_bf16_rne(v.x);
    h.y = f32_to_bf16_rne(v.y);
    h.z = f32_to_bf16_rne(v.z);
    h.w = f32_to_bf16_rne(v.w);
    ((ushort4*)(hi + (size_t)r0 * K_))[i] = h;
  }
  __syncthreads();

  const int row = tid >> 5, l = tid & 31, blk = l >> 3, j = l & 7;
  const float* p = buf + row * 512 + blk * 128;
  float r = __fmul_rn(p[j], p[j]);
  #pragma unroll
  for (int i = 8; i < 128; i += 8) r = __fadd_rn(r, __fmul_rn(p[i + j], p[i + j]));
  r = __fadd_rn(r, __shfl_xor(r, 1));
  r = __fadd_rn(r, __shfl_xor(r, 2));
  r = __fadd_rn(r, __shfl_xor(r, 4));
  r = __fadd_rn(r, __shfl_xor(r, 8));
  r = __fadd_rn(r, __shfl_xor(r, 16));
  if (l == 0 && r0 + row < nrows) sumsq[r0 + row] = r;
}

__global__ void rowsumsq_kernel(const float* __restrict__ src, float* __restrict__ dst,
                                int nrows) {
  int r = blockIdx.x * blockDim.x + threadIdx.x;
  if (r < nrows) dst[r] = np_pairwise_sumsq512(src + (size_t)r * K_);
}

// G [O_][H_] -> GT [H_][O_]
__global__ void transposeG_kernel(const float* __restrict__ G, float* __restrict__ GT) {
  __shared__ float t[32][33];
  int h0 = blockIdx.x * 32, o0 = blockIdx.y * 32;
  for (int i = threadIdx.y; i < 32; i += 8)
    t[i][threadIdx.x] = G[(size_t)(o0 + i) * H_ + h0 + threadIdx.x];
  __syncthreads();
  for (int i = threadIdx.y; i < 32; i += 8)
    GT[(size_t)(h0 + i) * O_ + o0 + threadIdx.x] = t[threadIdx.x][i];
}

// ---------------------------------------------------------------------------
// Phase 1: hi*hi bf16 MFMA — NO LDS in the K-loop. Fragments are gathered
// directly from global (L1/L2-served: W panel 4MB fits every XCD L2; x panel
// 2MB/XCD, XCD = row-block mod 8 stable). No staging, no barriers — the
// saturated LDS pipe (R7-R10 ceiling: 32 x ds_read_b128/block-K-tile vs 80
// MFMA cyc/SIMD) is out of the loop entirely.
// Epilogue: per-wave LDS transpose -> lane owns a 16-col group -> coalesced
// vector stores (unchanged from R10).
// ---------------------------------------------------------------------------
__global__ __launch_bounds__(256) void phase1_mfma_kernel(
    const unsigned short* __restrict__ xhi, const unsigned short* __restrict__ whi,
    const float* __restrict__ wsq, const float* __restrict__ xsq,
    float* __restrict__ gmin16 /*[B_][256]*/,
    unsigned short* __restrict__ mk16 /*[B_][256]*/) {
  // smem only for the epilogue:
  // [0,16640) T transpose 4 x [16][65] f32
  // [16640,21248) EpiF [128][9] f32; [21248,23296) EpiM [128][8] u16
  __shared__ __align__(16) char smem[23296];
  const int tid = (int)threadIdx.x;
  const int wid = tid >> 6, lane = tid & 63;
  const int wr = wid >> 1, wc = wid & 1;
  const int cb = blockIdx.y;
  const int row0 = blockIdx.x * 128, col0 = cb * 128;

  f32x4 acc[4][4];
  #pragma unroll
  for (int i = 0; i < 4; ++i)
    #pragma unroll
    for (int j = 0; j < 4; ++j) acc[i][j] = (f32x4){0.f, 0.f, 0.f, 0.f};

  const int r16 = lane & 15, sg = lane >> 4;

  // per-fragment global base pointers (A: 16 rows x 4 k-slots per instr,
  // 64B-contiguous per row -> 16-segment coalesced gather, L2-resident)
  const unsigned short* ap[4];
  const unsigned short* bp[4];
  #pragma unroll
  for (int mf = 0; mf < 4; ++mf)
    ap[mf] = xhi + (size_t)(row0 + wr * 64 + mf * 16 + r16) * K_ + sg * 8;
  #pragma unroll
  for (int nf = 0; nf < 4; ++nf)
    bp[nf] = whi + (size_t)(col0 + wc * 64 + nf * 16 + r16) * K_ + sg * 8;

  #pragma unroll 2
  for (int kt = 0; kt < K_ / 32; ++kt) {
    bf16x8 ah[4], bh[4];
    #pragma unroll
    for (int mf = 0; mf < 4; ++mf) ah[mf] = *(const bf16x8*)(ap[mf] + kt * 32);
    #pragma unroll
    for (int nf = 0; nf < 4; ++nf) bh[nf] = *(const bf16x8*)(bp[nf] + kt * 32);
    #pragma unroll
    for (int nf = 0; nf < 4; ++nf)
      #pragma unroll
      for (int mf = 0; mf < 4; ++mf)
        acc[mf][nf] = __builtin_amdgcn_mfma_f32_16x16x32_bf16(ah[mf], bh[nf], acc[mf][nf], 0, 0, 0);
  }

  // ---- epilogue ----
  // s_approx = wsq[col] - 2*dot. D layout: col=lane&15, row=(lane>>4)*4+reg.
  float* T = (float*)smem + wid * (16 * 65);
  float* EpiF = (float*)(smem + 16640);            // [128][9]
  unsigned short* EpiM = (unsigned short*)(smem + 21248);  // [128][8]

  const float xq = xsq[row0 + wr * 64 + lane];     // one coalesced load
  const int c = lane & 15;

  #pragma unroll
  for (int nf = 0; nf < 4; ++nf) {
    float wq = wsq[col0 + wc * 64 + nf * 16 + c];
    #pragma unroll
    for (int mf = 0; mf < 4; ++mf)
      #pragma unroll
      for (int r = 0; r < 4; ++r)
        T[c * 65 + (mf * 16 + sg * 4 + r)] = wq - 2.0f * acc[mf][nf][r];
    asm volatile("s_waitcnt lgkmcnt(0)" ::: "memory");
    __builtin_amdgcn_sched_barrier(0);
    // lane now owns local row = lane: read its 16 column values
    float v[16];
    #pragma unroll
    for (int c2 = 0; c2 < 16; ++c2) v[c2] = T[c2 * 65 + lane];
    float mn = v[0];
    #pragma unroll
    for (int c2 = 1; c2 < 16; ++c2) mn = fminf(mn, v[c2]);
    unsigned msk = 0;
    #pragma unroll
    for (int c2 = 0; c2 < 16; ++c2)
      if ((v[c2] <= mn + EPS_FLAG) || (v[c2] + xq <= EPS_FLAG)) msk |= 1u << c2;
    EpiF[(wr * 64 + lane) * 9 + wc * 4 + nf] = mn;
    EpiM[(wr * 64 + lane) * 8 + wc * 4 + nf] = (unsigned short)msk;
  }
  __syncthreads();

  // cooperative coalesced store: gm 128 rows x 8 f32, mk 128 rows x 8 u16
  {
    int row = tid >> 1, half = tid & 1;
    float4 vf;
    vf.x = EpiF[row * 9 + half * 4 + 0];
    vf.y = EpiF[row * 9 + half * 4 + 1];
    vf.z = EpiF[row * 9 + half * 4 + 2];
    vf.w = EpiF[row * 9 + half * 4 + 3];
    *(float4*)&gmin16[(size_t)(row0 + row) * 256 + cb * 8 + half * 4] = vf;
    if (tid < 128) {
      uint4 vm = *(const uint4*)&EpiM[tid * 8];
      *(uint4*)&mk16[(size_t)(row0 + tid) * 256 + cb * 8] = vm;
    }
  }
}

// ---------------------------------------------------------------------------
// Phase 2: one wave per row. Compact candidate cols (ballot-prefix -> LDS
// list), each lane runs one exact chain (bitwise ascending-k FMA, float4
// loads), wave-reduce (dist_bits,h) key, fused GT gather + index write.
// ---------------------------------------------------------------------------
#define CAND_CAP 512

__global__ __launch_bounds__(256) void phase2_wave_kernel(
    const float* __restrict__ gm /*[B_][256]*/,
    const unsigned short* __restrict__ mk /*[B_][256]*/,
    const float* __restrict__ x, const float* __restrict__ W,
    const float* __restrict__ xsq, const float* __restrict__ wsq,
    const float* __restrict__ GT, float* __restrict__ out) {
  __shared__ float xs[4][512];
  __shared__ unsigned short clist[4][CAND_CAP];
  const int tid = (int)threadIdx.x;
  const int w = tid >> 6, lane = tid & 63;
  const int b = blockIdx.x * 4 + w;

  // stage x row (coalesced float4; chains read it as wave-uniform broadcast)
  const float4* xsrc = (const float4*)(x + (size_t)b * K_);
  ((float4*)xs[w])[lane] = xsrc[lane];
  ((float4*)xs[w])[lane + 64] = xsrc[lane + 64];

  // load 4 group minima + masks per lane (coalesced), reduce row min
  float4 v4 = ((const float4*)(gm + (size_t)b * 256))[lane];
  ushort4 m4 = ((const ushort4*)(mk + (size_t)b * 256))[lane];
  float vq[4] = {v4.x, v4.y, v4.z, v4.w};
  unsigned short ms[4] = {m4.x, m4.y, m4.z, m4.w};
  float m = fminf(fminf(vq[0], vq[1]), fminf(vq[2], vq[3]));
  #pragma unroll
  for (int off = 1; off < 64; off <<= 1) m = fminf(m, __shfl_xor(m, off));
  const float xq = xsq[b];
  const float thr = m + EPS_FLAG;

  // candidate cols: group flagged AND col bit set
  unsigned cm[4];
  int cnt = 0;
  #pragma unroll
  for (int q = 0; q < 4; ++q) {
    bool flag = (vq[q] <= thr) || (vq[q] + xq <= EPS_FLAG);
    cm[q] = flag ? (unsigned)ms[q] : 0u;
    cnt += __popc(cm[q]);
  }
  // exclusive prefix over the wave
  int incl = cnt;
  #pragma unroll
  for (int off = 1; off < 64; off <<= 1) {
    int o = __shfl_up(incl, off);
    if (lane >= off) incl += o;
  }
  int offset = incl - cnt;
  int total = __shfl(incl, 63);

  // write candidate list (clipped at CAND_CAP; overflow -> generic path)
  int pos = offset;
  #pragma unroll
  for (int q = 0; q < 4; ++q) {
    unsigned mm = cm[q];
    while (mm) {
      int bit = __ffs(mm) - 1;
      mm &= mm - 1;
      if (pos < CAND_CAP)
        clist[w][pos] = (unsigned short)((4 * lane + q) * 16 + bit);
      ++pos;
    }
  }
  __syncthreads();

  unsigned long long best = 0xFFFFFFFFFFFFFFFFULL;
  if (total <= CAND_CAP) {
    for (int i = lane; i < total; i += 64) {
      int col = (int)clist[w][i];
      const float4* wrow = (const float4*)(W + (size_t)col * K_);
      float acc = 0.0f;
      #pragma unroll 8
      for (int kq = 0; kq < K_ / 4; ++kq) {
        float4 xv = ((const float4*)xs[w])[kq];
        float4 wv = wrow[kq];
        acc = fmaf(xv.x, wv.x, acc);
        acc = fmaf(xv.y, wv.y, acc);
        acc = fmaf(xv.z, wv.z, acc);
        acc = fmaf(xv.w, wv.w, acc);
      }
      float t2 = xq - 2.0f * acc;
      float sq = t2 + wsq[col];
      float d = sqrtf(fmaxf(sq, 0.0f));
      unsigned long long key =
          ((unsigned long long)__float_as_uint(d) << 32) | (unsigned)col;
      best = key < best ? key : best;
    }
  } else {
    // rare generic path: scan all cols, test group flag + bit from global
    for (int c = lane; c < H_; c += 64) {
      int g = c >> 4;
      float gv = gm[(size_t)b * 256 + g];
      if ((gv <= thr || gv + xq <= EPS_FLAG) &&
          ((mk[(size_t)b * 256 + g] >> (c & 15)) & 1)) {
        const float4* wrow = (const float4*)(W + (size_t)c * K_);
        float acc = 0.0f;
        #pragma unroll 8
        for (int kq = 0; kq < K_ / 4; ++kq) {
          float4 xv = ((const float4*)xs[w])[kq];
          float4 wv = wrow[kq];
          acc = fmaf(xv.x, wv.x, acc);
          acc = fmaf(xv.y, wv.y, acc);
          acc = fmaf(xv.z, wv.z, acc);
          acc = fmaf(xv.w, wv.w, acc);
        }
        float t2 = xq - 2.0f * acc;
        float sq = t2 + wsq[c];
        float d = sqrtf(fmaxf(sq, 0.0f));
        unsigned long long key =
            ((unsigned long long)__float_as_uint(d) << 32) | (unsigned)c;
        best = key < best ? key : best;
      }
    }
  }
  #pragma unroll
  for (int off = 1; off < 64; off <<= 1) {
    unsigned long long o = __shfl_xor(best, off);
    best = best < o ? best : o;
  }
  const unsigned h = (unsigned)(best & 0xFFFFFFFFULL);

  // fused epilogue: gather GT[h] + winner index
  const float4* gsrc = (const float4*)(GT + (size_t)h * O_);
  float4* gdst = (float4*)(out + (size_t)b * O_);
  gdst[lane] = gsrc[lane];
  gdst[lane + 64] = gsrc[lane + 64];
  if (lane == 0) out[(size_t)B_ * O_ + b] = (float)h;
}

// ---------------------------------------------------------------------------
// Round-1 fallback (exact f32 vector GEMM + argmin) — used only if ws too small
// ---------------------------------------------------------------------------
#define BM 128
#define BN 128
#define BKK 16

__global__ void init_keys_kernel(unsigned long long* __restrict__ keys) {
  int i = blockIdx.x * blockDim.x + threadIdx.x;
  if (i < B_) keys[i] = 0xFFFFFFFFFFFFFFFFULL;
}

__global__ __launch_bounds__(256) void dist_argmin_kernel(
    const float* __restrict__ x, const float* __restrict__ W,
    const float* __restrict__ xsq, const float* __restrict__ wsq,
    unsigned long long* __restrict__ keys) {
  __shared__ float xs[BKK][BM + 4];
  __shared__ float wsh[BKK][BN + 4];
  const int row0 = blockIdx.x * BM;
  const int col0 = blockIdx.y * BN;
  const int tid = (int)threadIdx.x;
  const int tx = tid & 15, ty = tid >> 4;

  float acc[8][8];
  #pragma unroll
  for (int i = 0; i < 8; ++i)
    #pragma unroll
    for (int j = 0; j < 8; ++j) acc[i][j] = 0.0f;

  for (int kt = 0; kt < K_; kt += BKK) {
    #pragma unroll
    for (int l = 0; l < 2; ++l) {
      int e = tid + l * 256;
      int r = e >> 2, kq = e & 3;
      float4 v = *(const float4*)(x + (size_t)(row0 + r) * K_ + kt + kq * 4);
      xs[kq * 4 + 0][r] = v.x;
      xs[kq * 4 + 1][r] = v.y;
      xs[kq * 4 + 2][r] = v.z;
      xs[kq * 4 + 3][r] = v.w;
      float4 u = *(const float4*)(W + (size_t)(col0 + r) * K_ + kt + kq * 4);
      wsh[kq * 4 + 0][r] = u.x;
      wsh[kq * 4 + 1][r] = u.y;
      wsh[kq * 4 + 2][r] = u.z;
      wsh[kq * 4 + 3][r] = u.w;
    }
    __syncthreads();
    #pragma unroll
    for (int k = 0; k < BKK; ++k) {
      float4 a0 = *(const float4*)&xs[k][ty * 4];
      float4 a1 = *(const float4*)&xs[k][ty * 4 + 64];
      float4 b0 = *(const float4*)&wsh[k][tx * 4];
      float4 b1 = *(const float4*)&wsh[k][tx * 4 + 64];
      float ar[8] = {a0.x, a0.y, a0.z, a0.w, a1.x, a1.y, a1.z, a1.w};
      float br[8] = {b0.x, b0.y, b0.z, b0.w, b1.x, b1.y, b1.z, b1.w};
      #pragma unroll
      for (int i = 0; i < 8; ++i)
        #pragma unroll
        for (int j = 0; j < 8; ++j)
          acc[i][j] = fmaf(ar[i], br[j], acc[i][j]);
    }
    __syncthreads();
  }

  float xv[8], wv[8];
  int rowidx[8], colidx[8];
  #pragma unroll
  for (int i = 0; i < 8; ++i) {
    rowidx[i] = row0 + ty * 4 + (i & 3) + (i >> 2) * 64;
    xv[i] = xsq[rowidx[i]];
  }
  #pragma unroll
  for (int j = 0; j < 8; ++j) {
    colidx[j] = col0 + tx * 4 + (j & 3) + (j >> 2) * 64;
    wv[j] = wsq[colidx[j]];
  }
  #pragma unroll
  for (int i = 0; i < 8; ++i) {
    unsigned long long best = 0xFFFFFFFFFFFFFFFFULL;
    #pragma unroll
    for (int j = 0; j < 8; ++j) {
      float t2 = xv[i] - 2.0f * acc[i][j];
      float sq = t2 + wv[j];
      float d = sqrtf(fmaxf(sq, 0.0f));
      unsigned long long key =
          ((unsigned long long)__float_as_uint(d) << 32) | (unsigned)colidx[j];
      best = key < best ? key : best;
    }
    #pragma unroll
    for (int off = 1; off < 16; off <<= 1) {
      unsigned long long o = __shfl_xor(best, off, 16);
      best = o < best ? o : best;
    }
    if (tx == 0) atomicMin(&keys[rowidx[i]], best);
  }
}

__global__ void finalize_kernel(const unsigned long long* __restrict__ keys,
                                const float* __restrict__ GT,
                                const float* __restrict__ G,
                                float* __restrict__ out, int useGT) {
  int b = blockIdx.x;
  unsigned h = (unsigned)(keys[b] & 0xFFFFFFFFULL);
  if (threadIdx.x == 0) out[(size_t)B_ * O_ + b] = (float)h;
  if (useGT) {
    const float4* src = (const float4*)(GT + (size_t)h * O_);
    float4* dst = (float4*)(out + (size_t)b * O_);
    for (int i = threadIdx.x; i < O_ / 4; i += blockDim.x) dst[i] = src[i];
  } else {
    for (int o = threadIdx.x; o < O_; o += blockDim.x)
      out[(size_t)b * O_ + o] = G[(size_t)o * H_ + h];
  }
}

// ---------------------------------------------------------------------------
extern "C" void kernel_launch(void* const* d_in, const int* in_sizes, int n_in,
                              void* d_out, int out_size, void* d_ws, size_t ws_size,
                              hipStream_t stream) {
  const float* x = (const float*)d_in[0];
  const float* W = (const float*)d_in[1];
  const float* G = (const float*)d_in[2];
  float* out = (float*)d_out;
  char* ws = (char*)d_ws;

  // MFMA-path workspace layout
  size_t o_xsq  = 0;                                  // 64 KB
  size_t o_wsq  = o_xsq + 65536;                      // 16 KB
  size_t o_xhi  = o_wsq + 16384;                      // 16 MB
  size_t o_whi  = o_xhi + (size_t)B_ * K_ * 2;        // 4 MB
  size_t o_gm   = o_whi + (size_t)H_ * K_ * 2;        // 16 MB
  size_t o_mk   = o_gm + (size_t)B_ * 256 * 4;        // 8 MB
  size_t o_gt   = o_mk + (size_t)B_ * 256 * 2;        // 8 MB
  size_t need   = o_gt + (size_t)H_ * O_ * 4;

  if (ws_size >= need) {
    float* xsq = (float*)(ws + o_xsq);
    float* wsq = (float*)(ws + o_wsq);
    unsigned short* xhi = (unsigned short*)(ws + o_xhi);
    unsigned short* whi = (unsigned short*)(ws + o_whi);
    float* gm = (float*)(ws + o_gm);
    unsigned short* mk = (unsigned short*)(ws + o_mk);
    float* GT = (float*)(ws + o_gt);

    hipLaunchKernelGGL(prep_rows_kernel, dim3(B_ / 8), dim3(256), 0, stream,
                       x, xhi, xsq, B_);
    hipLaunchKernelGGL(prep_rows_kernel, dim3(H_ / 8), dim3(256), 0, stream,
                       W, whi, wsq, H_);
    hipLaunchKernelGGL(transposeG_kernel, dim3(H_ / 32, O_ / 32), dim3(32, 8), 0, stream,
                       G, GT);
    hipLaunchKernelGGL(phase1_mfma_kernel, dim3(B_ / 128, H_ / 128), dim3(256), 0, stream,
                       xhi, whi, wsq, xsq, gm, mk);
    hipLaunchKernelGGL(phase2_wave_kernel, dim3(B_ / 4), dim3(256), 0, stream,
                       gm, mk, x, W, xsq, wsq, GT, out);
    return;
  }

  // Fallback: round-1 exact path
  unsigned long long* keys = (unsigned long long*)ws;
  float* xsq = (float*)(ws + 131072);
  float* wsq = (float*)(ws + 131072 + 65536);
  float* GT = (float*)(ws + 131072 + 65536 + 16384);
  size_t base = 131072 + 65536 + 16384;
  int useGT = ws_size >= base + (size_t)H_ * O_ * 4 ? 1 : 0;

  hipLaunchKernelGGL(init_keys_kernel, dim3(B_ / 256), dim3(256), 0, stream, keys);
  hipLaunchKernelGGL(rowsumsq_kernel, dim3(B_ / 256), dim3(256), 0, stream, x, xsq, B_);
  hipLaunchKernelGGL(rowsumsq_kernel, dim3(H_ / 256), dim3(256), 0, stream, W, wsq, H_);
  if (useGT)
    hipLaunchKernelGGL(transposeG_kernel, dim3(H_ / 32, O_ / 32), dim3(32, 8), 0, stream,
                       G, GT);
  hipLaunchKernelGGL(dist_argmin_kernel, dim3(B_ / BM, H_ / BN), dim3(256), 0, stream,
                     x, W, xsq, wsq, keys);
  hipLaunchKernelGGL(finalize_kernel, dim3(B_), dim3(128), 0, stream, keys, GT, G, out,
                     useGT);
}

// Round 12
// 172.584 us; speedup vs baseline: 1.9686x; 1.9686x over previous
//
#include <hip/hip_runtime.h>
#include <cstdint>
#include <cstddef>

#define B_ 16384
#define K_ 512
#define H_ 4096
#define O_ 512

typedef __attribute__((ext_vector_type(4))) float f32x4;
typedef __attribute__((ext_vector_type(8))) short bf16x8;

#define EPS_FLAG 0.125f

// ---------------------------------------------------------------------------
// Exact helpers (bitwise vs numpy reference — proven in rounds 1-10)
// ---------------------------------------------------------------------------
__device__ inline unsigned short f32_to_bf16_rne(float f) {
  unsigned u = __float_as_uint(f);
  unsigned r = (u + 0x7fffu + ((u >> 16) & 1u)) >> 16;
  return (unsigned short)r;
}

__device__ float np_pairwise_sumsq512(const float* __restrict__ a) {
  float s[4];
  #pragma unroll
  for (int blk = 0; blk < 4; ++blk) {
    const float* p = a + blk * 128;
    float r[8];
    #pragma unroll
    for (int j = 0; j < 8; ++j) r[j] = __fmul_rn(p[j], p[j]);
    for (int i = 8; i < 128; i += 8) {
      #pragma unroll
      for (int j = 0; j < 8; ++j) r[j] = __fadd_rn(r[j], __fmul_rn(p[i + j], p[i + j]));
    }
    s[blk] = __fadd_rn(__fadd_rn(__fadd_rn(r[0], r[1]), __fadd_rn(r[2], r[3])),
                       __fadd_rn(__fadd_rn(r[4], r[5]), __fadd_rn(r[6], r[7])));
  }
  return __fadd_rn(__fadd_rn(s[0], s[1]), __fadd_rn(s[2], s[3]));
}

// Fused: coalesced load of 8 rows -> LDS; emit bf16(hi) coalesced; numpy
// pairwise-order sumsq with 32 lanes/row (bitwise == np_pairwise_sumsq512).
__global__ __launch_bounds__(256) void prep_rows_kernel(
    const float* __restrict__ src, unsigned short* __restrict__ hi,
    float* __restrict__ sumsq, int nrows) {
  __shared__ float buf[8 * 512];
  const int r0 = blockIdx.x * 8;
  const int tid = (int)threadIdx.x;

  #pragma unroll
  for (int it = 0; it < 4; ++it) {
    int i = tid + it * 256;
    float4 v = ((const float4*)(src + (size_t)r0 * K_))[i];
    ((float4*)buf)[i] = v;
    ushort4 h;
    h.x = f32_to_bf16_rne(v.x);
    h.y = f32_to_bf16_rne(v.y);
    h.z = f32_to_bf16_rne(v.z);
    h.w = f32_to_bf16_rne(v.w);
    ((ushort4*)(hi + (size_t)r0 * K_))[i] = h;
  }
  __syncthreads();

  const int row = tid >> 5, l = tid & 31, blk = l >> 3, j = l & 7;
  const float* p = buf + row * 512 + blk * 128;
  float r = __fmul_rn(p[j], p[j]);
  #pragma unroll
  for (int i = 8; i < 128; i += 8) r = __fadd_rn(r, __fmul_rn(p[i + j], p[i + j]));
  r = __fadd_rn(r, __shfl_xor(r, 1));
  r = __fadd_rn(r, __shfl_xor(r, 2));
  r = __fadd_rn(r, __shfl_xor(r, 4));
  r = __fadd_rn(r, __shfl_xor(r, 8));
  r = __fadd_rn(r, __shfl_xor(r, 16));
  if (l == 0 && r0 + row < nrows) sumsq[r0 + row] = r;
}

__global__ void rowsumsq_kernel(const float* __restrict__ src, float* __restrict__ dst,
                                int nrows) {
  int r = blockIdx.x * blockDim.x + threadIdx.x;
  if (r < nrows) dst[r] = np_pairwise_sumsq512(src + (size_t)r * K_);
}

// G [O_][H_] -> GT [H_][O_]
__global__ void transposeG_kernel(const float* __restrict__ G, float* __restrict__ GT) {
  __shared__ float t[32][33];
  int h0 = blockIdx.x * 32, o0 = blockIdx.y * 32;
  for (int i = threadIdx.y; i < 32; i += 8)
    t[i][threadIdx.x] = G[(size_t)(o0 + i) * H_ + h0 + threadIdx.x];
  __syncthreads();
  for (int i = threadIdx.y; i < 32; i += 8)
    GT[(size_t)(h0 + i) * O_ + o0 + threadIdx.x] = t[threadIdx.x][i];
}

// ---------------------------------------------------------------------------
// Phase 1: hi*hi bf16 MFMA. BK=64 (128B LDS rows, 8 x 16B slots) with XOR-8
// swizzle slot^=(row&7): bank phase = 4*slot (row-independent), and the 16
// rows of a fragment read cover all 8 slots -> every 16-lane LDS phase hits
// all 32 banks exactly twice = conflict-free floor. (BK=32's 64B rows had
// only 4 slots: structurally 8-way, unfixable — R8 null result.)
// Swizzle is both-sides (rule #21): pre-swizzled GLOBAL source (involution),
// linear gl_lds dest, swizzled read offset. 2-phase double buffer (R7-safe).
// ---------------------------------------------------------------------------
__device__ inline void stage_tile64(char* lds_base, const unsigned short* __restrict__ src,
                                    int row0, int kt, int wid, int lane) {
  // tile [128][64]bf16 = 16KB = 16 chunks x 1KB; unit u: row=u>>3, slot=u&7
  #pragma unroll
  for (int j = 0; j < 4; ++j) {
    int chunk = wid + j * 4;
    int u = chunk * 64 + lane;
    int row = u >> 3, slot = u & 7;
    int slot_src = slot ^ (row & 7);    // involution; matched on read side
    const char* g = (const char*)src + (size_t)(row0 + row) * (K_ * 2) + kt * 128 + slot_src * 16;
    char* l = lds_base + chunk * 1024;
    __builtin_amdgcn_global_load_lds((const __attribute__((address_space(1))) void*)g,
                                     (__attribute__((address_space(3))) void*)l,
                                     16, 0, 0);
  }
}

__global__ __launch_bounds__(256) void phase1_mfma_kernel(
    const unsigned short* __restrict__ xhi, const unsigned short* __restrict__ whi,
    const float* __restrict__ wsq, const float* __restrict__ xsq,
    float* __restrict__ gmin16 /*[B_][256]*/,
    unsigned short* __restrict__ mk16 /*[B_][256]*/) {
  // union: [0,65536) staging 2 x (A 16KB + B 16KB)  (K-loop)
  //        [0,16640) T transpose 4 x [16][65] f32   (epilogue, after sync)
  //        [16640,21248) EpiF [128][9] f32; [21248,23296) EpiM [128][8] u16
  __shared__ __align__(16) char smem[65536];
  const int tid = (int)threadIdx.x;
  const int wid = tid >> 6, lane = tid & 63;
  const int wr = wid >> 1, wc = wid & 1;
  const int cb = blockIdx.y;
  const int row0 = blockIdx.x * 128, col0 = cb * 128;

  f32x4 acc[4][4];
  #pragma unroll
  for (int i = 0; i < 4; ++i)
    #pragma unroll
    for (int j = 0; j < 4; ++j) acc[i][j] = (f32x4){0.f, 0.f, 0.f, 0.f};

  const int arow = wr * 64 + (lane & 15);
  const int brow = wc * 64 + (lane & 15);
  const int r7 = lane & 7, sg = lane >> 4;
  // swizzled 16B-slot byte offsets for the two K32 subtiles of a K64 row
  const int offK0 = ((sg ^ r7) & 7) * 16;
  const int offK1 = (((4 + sg) ^ r7) & 7) * 16;

  // prologue: stage kt=0 into buf0
  stage_tile64(smem, xhi, row0, 0, wid, lane);
  stage_tile64(smem + 16384, whi, col0, 0, wid, lane);
  __syncthreads();

  int buf = 0;
  for (int kt = 0; kt < 8; ++kt) {
    // issue next tile's stage into the other buffer (overlaps compute below)
    if (kt < 7) {
      stage_tile64(smem + (buf ^ 1) * 32768, xhi, row0, kt + 1, wid, lane);
      stage_tile64(smem + (buf ^ 1) * 32768 + 16384, whi, col0, kt + 1, wid, lane);
    }
    const char* A = smem + buf * 32768;
    const char* Bm = smem + buf * 32768 + 16384;
    #pragma unroll
    for (int ks = 0; ks < 2; ++ks) {
      const int offK = ks ? offK1 : offK0;
      bf16x8 ah[4];
      #pragma unroll
      for (int mf = 0; mf < 4; ++mf)
        ah[mf] = *(const bf16x8*)(A + (arow + mf * 16) * 128 + offK);
      #pragma unroll
      for (int nf = 0; nf < 4; ++nf) {
        bf16x8 bh = *(const bf16x8*)(Bm + (brow + nf * 16) * 128 + offK);
        #pragma unroll
        for (int mf = 0; mf < 4; ++mf)
          acc[mf][nf] = __builtin_amdgcn_mfma_f32_16x16x32_bf16(ah[mf], bh, acc[mf][nf], 0, 0, 0);
      }
    }
    __syncthreads();   // drains next stage (vmcnt0+lgkmcnt0) + protects reuse
    buf ^= 1;
  }

  // ---- epilogue ----
  // s_approx = wsq[col] - 2*dot. D layout: col=lane&15, row=(lane>>4)*4+reg.
  float* T = (float*)smem + wid * (16 * 65);
  float* EpiF = (float*)(smem + 16640);            // [128][9]
  unsigned short* EpiM = (unsigned short*)(smem + 21248);  // [128][8]

  const float xq = xsq[row0 + wr * 64 + lane];     // one coalesced load
  const int c = lane & 15;

  #pragma unroll
  for (int nf = 0; nf < 4; ++nf) {
    float wq = wsq[col0 + wc * 64 + nf * 16 + c];
    #pragma unroll
    for (int mf = 0; mf < 4; ++mf)
      #pragma unroll
      for (int r = 0; r < 4; ++r)
        T[c * 65 + (mf * 16 + sg * 4 + r)] = wq - 2.0f * acc[mf][nf][r];
    asm volatile("s_waitcnt lgkmcnt(0)" ::: "memory");
    __builtin_amdgcn_sched_barrier(0);
    // lane now owns local row = lane: read its 16 column values
    float v[16];
    #pragma unroll
    for (int c2 = 0; c2 < 16; ++c2) v[c2] = T[c2 * 65 + lane];
    float mn = v[0];
    #pragma unroll
    for (int c2 = 1; c2 < 16; ++c2) mn = fminf(mn, v[c2]);
    unsigned msk = 0;
    #pragma unroll
    for (int c2 = 0; c2 < 16; ++c2)
      if ((v[c2] <= mn + EPS_FLAG) || (v[c2] + xq <= EPS_FLAG)) msk |= 1u << c2;
    EpiF[(wr * 64 + lane) * 9 + wc * 4 + nf] = mn;
    EpiM[(wr * 64 + lane) * 8 + wc * 4 + nf] = (unsigned short)msk;
  }
  __syncthreads();

  // cooperative coalesced store: gm 128 rows x 8 f32, mk 128 rows x 8 u16
  {
    int row = tid >> 1, half = tid & 1;
    float4 vf;
    vf.x = EpiF[row * 9 + half * 4 + 0];
    vf.y = EpiF[row * 9 + half * 4 + 1];
    vf.z = EpiF[row * 9 + half * 4 + 2];
    vf.w = EpiF[row * 9 + half * 4 + 3];
    *(float4*)&gmin16[(size_t)(row0 + row) * 256 + cb * 8 + half * 4] = vf;
    if (tid < 128) {
      uint4 vm = *(const uint4*)&EpiM[tid * 8];
      *(uint4*)&mk16[(size_t)(row0 + tid) * 256 + cb * 8] = vm;
    }
  }
}

// ---------------------------------------------------------------------------
// Phase 2: one wave per row. Compact candidate cols (ballot-prefix -> LDS
// list), each lane runs one exact chain (bitwise ascending-k FMA, float4
// loads), wave-reduce (dist_bits,h) key, fused GT gather + index write.
// ---------------------------------------------------------------------------
#define CAND_CAP 512

__global__ __launch_bounds__(256) void phase2_wave_kernel(
    const float* __restrict__ gm /*[B_][256]*/,
    const unsigned short* __restrict__ mk /*[B_][256]*/,
    const float* __restrict__ x, const float* __restrict__ W,
    const float* __restrict__ xsq, const float* __restrict__ wsq,
    const float* __restrict__ GT, float* __restrict__ out) {
  __shared__ float xs[4][512];
  __shared__ unsigned short clist[4][CAND_CAP];
  const int tid = (int)threadIdx.x;
  const int w = tid >> 6, lane = tid & 63;
  const int b = blockIdx.x * 4 + w;

  // stage x row (coalesced float4; chains read it as wave-uniform broadcast)
  const float4* xsrc = (const float4*)(x + (size_t)b * K_);
  ((float4*)xs[w])[lane] = xsrc[lane];
  ((float4*)xs[w])[lane + 64] = xsrc[lane + 64];

  // load 4 group minima + masks per lane (coalesced), reduce row min
  float4 v4 = ((const float4*)(gm + (size_t)b * 256))[lane];
  ushort4 m4 = ((const ushort4*)(mk + (size_t)b * 256))[lane];
  float vq[4] = {v4.x, v4.y, v4.z, v4.w};
  unsigned short ms[4] = {m4.x, m4.y, m4.z, m4.w};
  float m = fminf(fminf(vq[0], vq[1]), fminf(vq[2], vq[3]));
  #pragma unroll
  for (int off = 1; off < 64; off <<= 1) m = fminf(m, __shfl_xor(m, off));
  const float xq = xsq[b];
  const float thr = m + EPS_FLAG;

  // candidate cols: group flagged AND col bit set
  unsigned cm[4];
  int cnt = 0;
  #pragma unroll
  for (int q = 0; q < 4; ++q) {
    bool flag = (vq[q] <= thr) || (vq[q] + xq <= EPS_FLAG);
    cm[q] = flag ? (unsigned)ms[q] : 0u;
    cnt += __popc(cm[q]);
  }
  // exclusive prefix over the wave
  int incl = cnt;
  #pragma unroll
  for (int off = 1; off < 64; off <<= 1) {
    int o = __shfl_up(incl, off);
    if (lane >= off) incl += o;
  }
  int offset = incl - cnt;
  int total = __shfl(incl, 63);

  // write candidate list (clipped at CAND_CAP; overflow -> generic path)
  int pos = offset;
  #pragma unroll
  for (int q = 0; q < 4; ++q) {
    unsigned mm = cm[q];
    while (mm) {
      int bit = __ffs(mm) - 1;
      mm &= mm - 1;
      if (pos < CAND_CAP)
        clist[w][pos] = (unsigned short)((4 * lane + q) * 16 + bit);
      ++pos;
    }
  }
  __syncthreads();

  unsigned long long best = 0xFFFFFFFFFFFFFFFFULL;
  if (total <= CAND_CAP) {
    for (int i = lane; i < total; i += 64) {
      int col = (int)clist[w][i];
      const float4* wrow = (const float4*)(W + (size_t)col * K_);
      float acc = 0.0f;
      #pragma unroll 8
      for (int kq = 0; kq < K_ / 4; ++kq) {
        float4 xv = ((const float4*)xs[w])[kq];
        float4 wv = wrow[kq];
        acc = fmaf(xv.x, wv.x, acc);
        acc = fmaf(xv.y, wv.y, acc);
        acc = fmaf(xv.z, wv.z, acc);
        acc = fmaf(xv.w, wv.w, acc);
      }
      float t2 = xq - 2.0f * acc;
      float sq = t2 + wsq[col];
      float d = sqrtf(fmaxf(sq, 0.0f));
      unsigned long long key =
          ((unsigned long long)__float_as_uint(d) << 32) | (unsigned)col;
      best = key < best ? key : best;
    }
  } else {
    // rare generic path: scan all cols, test group flag + bit from global
    for (int c = lane; c < H_; c += 64) {
      int g = c >> 4;
      float gv = gm[(size_t)b * 256 + g];
      if ((gv <= thr || gv + xq <= EPS_FLAG) &&
          ((mk[(size_t)b * 256 + g] >> (c & 15)) & 1)) {
        const float4* wrow = (const float4*)(W + (size_t)c * K_);
        float acc = 0.0f;
        #pragma unroll 8
        for (int kq = 0; kq < K_ / 4; ++kq) {
          float4 xv = ((const float4*)xs[w])[kq];
          float4 wv = wrow[kq];
          acc = fmaf(xv.x, wv.x, acc);
          acc = fmaf(xv.y, wv.y, acc);
          acc = fmaf(xv.z, wv.z, acc);
          acc = fmaf(xv.w, wv.w, acc);
        }
        float t2 = xq - 2.0f * acc;
        float sq = t2 + wsq[c];
        float d = sqrtf(fmaxf(sq, 0.0f));
        unsigned long long key =
            ((unsigned long long)__float_as_uint(d) << 32) | (unsigned)c;
        best = key < best ? key : best;
      }
    }
  }
  #pragma unroll
  for (int off = 1; off < 64; off <<= 1) {
    unsigned long long o = __shfl_xor(best, off);
    best = best < o ? best : o;
  }
  const unsigned h = (unsigned)(best & 0xFFFFFFFFULL);

  // fused epilogue: gather GT[h] + winner index
  const float4* gsrc = (const float4*)(GT + (size_t)h * O_);
  float4* gdst = (float4*)(out + (size_t)b * O_);
  gdst[lane] = gsrc[lane];
  gdst[lane + 64] = gsrc[lane + 64];
  if (lane == 0) out[(size_t)B_ * O_ + b] = (float)h;
}

// ---------------------------------------------------------------------------
// Round-1 fallback (exact f32 vector GEMM + argmin) — used only if ws too small
// ---------------------------------------------------------------------------
#define BM 128
#define BN 128
#define BKK 16

__global__ void init_keys_kernel(unsigned long long* __restrict__ keys) {
  int i = blockIdx.x * blockDim.x + threadIdx.x;
  if (i < B_) keys[i] = 0xFFFFFFFFFFFFFFFFULL;
}

__global__ __launch_bounds__(256) void dist_argmin_kernel(
    const float* __restrict__ x, const float* __restrict__ W,
    const float* __restrict__ xsq, const float* __restrict__ wsq,
    unsigned long long* __restrict__ keys) {
  __shared__ float xs[BKK][BM + 4];
  __shared__ float wsh[BKK][BN + 4];
  const int row0 = blockIdx.x * BM;
  const int col0 = blockIdx.y * BN;
  const int tid = (int)threadIdx.x;
  const int tx = tid & 15, ty = tid >> 4;

  float acc[8][8];
  #pragma unroll
  for (int i = 0; i < 8; ++i)
    #pragma unroll
    for (int j = 0; j < 8; ++j) acc[i][j] = 0.0f;

  for (int kt = 0; kt < K_; kt += BKK) {
    #pragma unroll
    for (int l = 0; l < 2; ++l) {
      int e = tid + l * 256;
      int r = e >> 2, kq = e & 3;
      float4 v = *(const float4*)(x + (size_t)(row0 + r) * K_ + kt + kq * 4);
      xs[kq * 4 + 0][r] = v.x;
      xs[kq * 4 + 1][r] = v.y;
      xs[kq * 4 + 2][r] = v.z;
      xs[kq * 4 + 3][r] = v.w;
      float4 u = *(const float4*)(W + (size_t)(col0 + r) * K_ + kt + kq * 4);
      wsh[kq * 4 + 0][r] = u.x;
      wsh[kq * 4 + 1][r] = u.y;
      wsh[kq * 4 + 2][r] = u.z;
      wsh[kq * 4 + 3][r] = u.w;
    }
    __syncthreads();
    #pragma unroll
    for (int k = 0; k < BKK; ++k) {
      float4 a0 = *(const float4*)&xs[k][ty * 4];
      float4 a1 = *(const float4*)&xs[k][ty * 4 + 64];
      float4 b0 = *(const float4*)&wsh[k][tx * 4];
      float4 b1 = *(const float4*)&wsh[k][tx * 4 + 64];
      float ar[8] = {a0.x, a0.y, a0.z, a0.w, a1.x, a1.y, a1.z, a1.w};
      float br[8] = {b0.x, b0.y, b0.z, b0.w, b1.x, b1.y, b1.z, b1.w};
      #pragma unroll
      for (int i = 0; i < 8; ++i)
        #pragma unroll
        for (int j = 0; j < 8; ++j)
          acc[i][j] = fmaf(ar[i], br[j], acc[i][j]);
    }
    __syncthreads();
  }

  float xv[8], wv[8];
  int rowidx[8], colidx[8];
  #pragma unroll
  for (int i = 0; i < 8; ++i) {
    rowidx[i] = row0 + ty * 4 + (i & 3) + (i >> 2) * 64;
    xv[i] = xsq[rowidx[i]];
  }
  #pragma unroll
  for (int j = 0; j < 8; ++j) {
    colidx[j] = col0 + tx * 4 + (j & 3) + (j >> 2) * 64;
    wv[j] = wsq[colidx[j]];
  }
  #pragma unroll
  for (int i = 0; i < 8; ++i) {
    unsigned long long best = 0xFFFFFFFFFFFFFFFFULL;
    #pragma unroll
    for (int j = 0; j < 8; ++j) {
      float t2 = xv[i] - 2.0f * acc[i][j];
      float sq = t2 + wv[j];
      float d = sqrtf(fmaxf(sq, 0.0f));
      unsigned long long key =
          ((unsigned long long)__float_as_uint(d) << 32) | (unsigned)colidx[j];
      best = key < best ? key : best;
    }
    #pragma unroll
    for (int off = 1; off < 16; off <<= 1) {
      unsigned long long o = __shfl_xor(best, off, 16);
      best = o < best ? o : best;
    }
    if (tx == 0) atomicMin(&keys[rowidx[i]], best);
  }
}

__global__ void finalize_kernel(const unsigned long long* __restrict__ keys,
                                const float* __restrict__ GT,
                                const float* __restrict__ G,
                                float* __restrict__ out, int useGT) {
  int b = blockIdx.x;
  unsigned h = (unsigned)(keys[b] & 0xFFFFFFFFULL);
  if (threadIdx.x == 0) out[(size_t)B_ * O_ + b] = (float)h;
  if (useGT) {
    const float4* src = (const float4*)(GT + (size_t)h * O_);
    float4* dst = (float4*)(out + (size_t)b * O_);
    for (int i = threadIdx.x; i < O_ / 4; i += blockDim.x) dst[i] = src[i];
  } else {
    for (int o = threadIdx.x; o < O_; o += blockDim.x)
      out[(size_t)b * O_ + o] = G[(size_t)o * H_ + h];
  }
}

// ---------------------------------------------------------------------------
extern "C" void kernel_launch(void* const* d_in, const int* in_sizes, int n_in,
                              void* d_out, int out_size, void* d_ws, size_t ws_size,
                              hipStream_t stream) {
  const float* x = (const float*)d_in[0];
  const float* W = (const float*)d_in[1];
  const float* G = (const float*)d_in[2];
  float* out = (float*)d_out;
  char* ws = (char*)d_ws;

  // MFMA-path workspace layout
  size_t o_xsq  = 0;                                  // 64 KB
  size_t o_wsq  = o_xsq + 65536;                      // 16 KB
  size_t o_xhi  = o_wsq + 16384;                      // 16 MB
  size_t o_whi  = o_xhi + (size_t)B_ * K_ * 2;        // 4 MB
  size_t o_gm   = o_whi + (size_t)H_ * K_ * 2;        // 16 MB
  size_t o_mk   = o_gm + (size_t)B_ * 256 * 4;        // 8 MB
  size_t o_gt   = o_mk + (size_t)B_ * 256 * 2;        // 8 MB
  size_t need   = o_gt + (size_t)H_ * O_ * 4;

  if (ws_size >= need) {
    float* xsq = (float*)(ws + o_xsq);
    float* wsq = (float*)(ws + o_wsq);
    unsigned short* xhi = (unsigned short*)(ws + o_xhi);
    unsigned short* whi = (unsigned short*)(ws + o_whi);
    float* gm = (float*)(ws + o_gm);
    unsigned short* mk = (unsigned short*)(ws + o_mk);
    float* GT = (float*)(ws + o_gt);

    hipLaunchKernelGGL(prep_rows_kernel, dim3(B_ / 8), dim3(256), 0, stream,
                       x, xhi, xsq, B_);
    hipLaunchKernelGGL(prep_rows_kernel, dim3(H_ / 8), dim3(256), 0, stream,
                       W, whi, wsq, H_);
    hipLaunchKernelGGL(transposeG_kernel, dim3(H_ / 32, O_ / 32), dim3(32, 8), 0, stream,
                       G, GT);
    hipLaunchKernelGGL(phase1_mfma_kernel, dim3(B_ / 128, H_ / 128), dim3(256), 0, stream,
                       xhi, whi, wsq, xsq, gm, mk);
    hipLaunchKernelGGL(phase2_wave_kernel, dim3(B_ / 4), dim3(256), 0, stream,
                       gm, mk, x, W, xsq, wsq, GT, out);
    return;
  }

  // Fallback: round-1 exact path
  unsigned long long* keys = (unsigned long long*)ws;
  float* xsq = (float*)(ws + 131072);
  float* wsq = (float*)(ws + 131072 + 65536);
  float* GT = (float*)(ws + 131072 + 65536 + 16384);
  size_t base = 131072 + 65536 + 16384;
  int useGT = ws_size >= base + (size_t)H_ * O_ * 4 ? 1 : 0;

  hipLaunchKernelGGL(init_keys_kernel, dim3(B_ / 256), dim3(256), 0, stream, keys);
  hipLaunchKernelGGL(rowsumsq_kernel, dim3(B_ / 256), dim3(256), 0, stream, x, xsq, B_);
  hipLaunchKernelGGL(rowsumsq_kernel, dim3(H_ / 256), dim3(256), 0, stream, W, wsq, H_);
  if (useGT)
    hipLaunchKernelGGL(transposeG_kernel, dim3(H_ / 32, O_ / 32), dim3(32, 8), 0, stream,
                       G, GT);
  hipLaunchKernelGGL(dist_argmin_kernel, dim3(B_ / BM, H_ / BN), dim3(256), 0, stream,
                     x, W, xsq, wsq, keys);
  hipLaunchKernelGGL(finalize_kernel, dim3(B_), dim3(128), 0, stream, keys, GT, G, out,
                     useGT);
}